// Round 7
// baseline (1751.618 us; speedup 1.0000x reference)
//
#include <hip/hip_runtime.h>

#define Dd 256
#define Nn 2048
#define Bb 8
#define Ll 4
#define Mm (Bb*Nn)   // 16384

typedef __attribute__((ext_vector_type(8))) short short8;
typedef __attribute__((ext_vector_type(4))) float f32x4;
typedef unsigned short u16;

__device__ __forceinline__ u16 f2bf(float f) {
  unsigned int u = __float_as_uint(f);
  u = (u + 0x7FFFu + ((u >> 16) & 1u)) >> 16;
  return (u16)u;
}
__device__ __forceinline__ float bf2f(u16 h) {
  return __uint_as_float(((unsigned int)h) << 16);
}
__device__ __forceinline__ void split2(float v, u16& hi, u16& lo) {
  hi = f2bf(v);
  lo = f2bf(v - bf2f(hi));
}

// ---- weight prep: split-transpose Wt[l][e][d] = W[l][d][e] into bf16 hi/lo ----
__global__ void prep_w3(const float* __restrict__ Wq, const float* __restrict__ Wk,
                        const float* __restrict__ Wv, const float* __restrict__ W1,
                        const float* __restrict__ W2,
                        u16* __restrict__ qh, u16* __restrict__ ql,
                        u16* __restrict__ kh, u16* __restrict__ kl,
                        u16* __restrict__ vh, u16* __restrict__ vl,
                        u16* __restrict__ w1h, u16* __restrict__ w1l,
                        u16* __restrict__ w2h, u16* __restrict__ w2l) {
  int idx = blockIdx.x * 256 + threadIdx.x;    // < L*D*D
  int l = idx >> 16, rem = idx & 65535;
  int e = rem >> 8, d = rem & 255;
  int src = (l << 16) | (d << 8) | e;
  u16 h, lo;
  split2(Wq[src], h, lo); qh[idx] = h;  ql[idx] = lo;
  split2(Wk[src], h, lo); kh[idx] = h;  kl[idx] = lo;
  split2(Wv[src], h, lo); vh[idx] = h;  vl[idx] = lo;
  split2(W1[src], h, lo); w1h[idx] = h; w1l[idx] = lo;
  split2(W2[src], h, lo); w2h[idx] = h; w2l[idx] = lo;
}

// ---- H = x + wpe ; split stores ----
__global__ void add_pe3(const float* __restrict__ x, const float* __restrict__ wpe,
                        float* __restrict__ H, u16* __restrict__ Hh, u16* __restrict__ Hl) {
  int idx = blockIdx.x * 256 + threadIdx.x;    // float4 index
  int nd = (idx << 2) & (Nn * Dd - 1);
  float4 xv = ((const float4*)x)[idx];
  float4 pv = *(const float4*)(wpe + nd);
  float4 h;
  h.x = xv.x + pv.x; h.y = xv.y + pv.y; h.z = xv.z + pv.z; h.w = xv.w + pv.w;
  ((float4*)H)[idx] = h;
  ushort4 hv, lv;
  split2(h.x, hv.x, lv.x); split2(h.y, hv.y, lv.y);
  split2(h.z, hv.z, lv.z); split2(h.w, hv.w, lv.w);
  ((ushort4*)Hh)[idx] = hv;
  ((ushort4*)Hl)[idx] = lv;
}

// ---- layernorm: 1 wave per row; fp32 out + split bf16 out ----
__global__ __launch_bounds__(256) void ln3(const float* __restrict__ Hin,
      float* __restrict__ Hout, u16* __restrict__ Hh, u16* __restrict__ Hl,
      const float* __restrict__ g, const float* __restrict__ b) {
  int w = threadIdx.x >> 6, l = threadIdx.x & 63;
  int row = blockIdx.x * 4 + w;
  const float4 h = *(const float4*)(Hin + row * Dd + l * 4);
  float s = h.x + h.y + h.z + h.w;
  #pragma unroll
  for (int m = 1; m < 64; m <<= 1) s += __shfl_xor(s, m, 64);
  float mu = s * (1.0f / Dd);
  float4 c; c.x = h.x - mu; c.y = h.y - mu; c.z = h.z - mu; c.w = h.w - mu;
  float sq = c.x*c.x + c.y*c.y + c.z*c.z + c.w*c.w;
  #pragma unroll
  for (int m = 1; m < 64; m <<= 1) sq += __shfl_xor(sq, m, 64);
  float rs = rsqrtf(sq * (1.0f / Dd) + 1e-5f);
  float4 gv = *(const float4*)(g + l * 4);
  float4 bv = *(const float4*)(b + l * 4);
  float4 y;
  y.x = c.x * rs * gv.x + bv.x;
  y.y = c.y * rs * gv.y + bv.y;
  y.z = c.z * rs * gv.z + bv.z;
  y.w = c.w * rs * gv.w + bv.w;
  *(float4*)(Hout + row * Dd + l * 4) = y;
  ushort4 hv, lv;
  split2(y.x, hv.x, lv.x); split2(y.y, hv.y, lv.y);
  split2(y.z, hv.z, lv.z); split2(y.w, hv.w, lv.w);
  *(ushort4*)(Hh + row * Dd + l * 4) = hv;
  *(ushort4*)(Hl + row * Dd + l * 4) = lv;
}

// ---- NT GEMM, bf16x3 (split hi/lo), fp32 acc, 64x64 tile ----
// EPI 0: split store; EPI 1: +bias, relu, split store; EPI 2: +bias, fp32 C +=
// EPI 3: split store in 32-col panel layout [col/32][row(256)][col&31] (for V)
template<int EPI>
__global__ __launch_bounds__(256) void gemm3(
    const u16* __restrict__ Ah, const u16* __restrict__ Al,
    const u16* __restrict__ Bh, const u16* __restrict__ Bl,
    void* __restrict__ Ch, void* __restrict__ Cl, const float* __restrict__ bias,
    int ldc, long sBz, long sCz) {
  __shared__ u16 Sa[2][64 * 40];
  __shared__ u16 Sb[2][64 * 40];
  const int t = threadIdx.x;
  const int l = t & 63, w = t >> 6;
  const int m0 = blockIdx.x * 64, n0 = blockIdx.y * 64;
  Bh += (long)blockIdx.z * sBz;
  Bl += (long)blockIdx.z * sBz;
  const int lr = l & 15, lk = l >> 4;
  const int sr = t >> 2, sc = t & 3;   // staging: row 0..63, col-chunk 0..3

  const f32x4 zv = {0.f, 0.f, 0.f, 0.f};
  f32x4 acc[4];
  #pragma unroll
  for (int i = 0; i < 4; ++i) acc[i] = zv;

  for (int kt = 0; kt < 8; ++kt) {
    const int k0 = kt * 32;
    *(uint4*)(&Sa[0][sr * 40 + sc * 8]) = *(const uint4*)(Ah + (long)(m0 + sr) * 256 + k0 + sc * 8);
    *(uint4*)(&Sa[1][sr * 40 + sc * 8]) = *(const uint4*)(Al + (long)(m0 + sr) * 256 + k0 + sc * 8);
    *(uint4*)(&Sb[0][sr * 40 + sc * 8]) = *(const uint4*)(Bh + (long)(n0 + sr) * 256 + k0 + sc * 8);
    *(uint4*)(&Sb[1][sr * 40 + sc * 8]) = *(const uint4*)(Bl + (long)(n0 + sr) * 256 + k0 + sc * 8);
    __syncthreads();
    short8 ah = *(const short8*)(&Sa[0][(w * 16 + lr) * 40 + lk * 8]);
    short8 al = *(const short8*)(&Sa[1][(w * 16 + lr) * 40 + lk * 8]);
    short8 bh[4], bl[4];
    #pragma unroll
    for (int ni = 0; ni < 4; ++ni) {
      bh[ni] = *(const short8*)(&Sb[0][(ni * 16 + lr) * 40 + lk * 8]);
      bl[ni] = *(const short8*)(&Sb[1][(ni * 16 + lr) * 40 + lk * 8]);
    }
    #pragma unroll
    for (int ni = 0; ni < 4; ++ni) {
      acc[ni] = __builtin_amdgcn_mfma_f32_16x16x32_bf16(ah, bh[ni], acc[ni], 0, 0, 0);
      acc[ni] = __builtin_amdgcn_mfma_f32_16x16x32_bf16(ah, bl[ni], acc[ni], 0, 0, 0);
      acc[ni] = __builtin_amdgcn_mfma_f32_16x16x32_bf16(al, bh[ni], acc[ni], 0, 0, 0);
    }
    __syncthreads();
  }

  #pragma unroll
  for (int ni = 0; ni < 4; ++ni) {
    const int row = m0 + w * 16 + lk * 4;
    const int col = n0 + ni * 16 + lr;
    if constexpr (EPI == 0) {
      u16* Chb = (u16*)Ch + (long)blockIdx.z * sCz;
      u16* Clb = (u16*)Cl + (long)blockIdx.z * sCz;
      #pragma unroll
      for (int r = 0; r < 4; ++r) {
        u16 hi, lo; split2(acc[ni][r], hi, lo);
        Chb[(long)(row + r) * ldc + col] = hi;
        Clb[(long)(row + r) * ldc + col] = lo;
      }
    } else if constexpr (EPI == 1) {
      u16* Chb = (u16*)Ch;
      u16* Clb = (u16*)Cl;
      const float bi = bias[col];
      #pragma unroll
      for (int r = 0; r < 4; ++r) {
        float v = fmaxf(acc[ni][r] + bi, 0.0f);
        u16 hi, lo; split2(v, hi, lo);
        Chb[(long)(row + r) * ldc + col] = hi;
        Clb[(long)(row + r) * ldc + col] = lo;
      }
    } else if constexpr (EPI == 2) {
      float* Cf = (float*)Ch;
      const float bi = bias[col];
      #pragma unroll
      for (int r = 0; r < 4; ++r)
        Cf[(long)(row + r) * ldc + col] += acc[ni][r] + bi;
    } else {
      // V panel layout: [col/32][row(0..255)][col&31]
      u16* Chb = (u16*)Ch + (long)blockIdx.z * sCz;
      u16* Clb = (u16*)Cl + (long)blockIdx.z * sCz;
      const long pbase = (long)(col >> 5) * (Dd * 32) + (col & 31);
      #pragma unroll
      for (int r = 0; r < 4; ++r) {
        u16 hi, lo; split2(acc[ni][r], hi, lo);
        Chb[pbase + (long)(row + r) * 32] = hi;
        Clb[pbase + (long)(row + r) * 32] = lo;
      }
    }
  }
}

// ---- causal relu attention, bf16x3 (R4 numerics), key-split, LDS-staged K/V ----
// grid: 1152 active blocks = 144 (qt,c) pairs x 8 batches, qt descending.
// T14 async-stage: prefetch next tile's global loads into regs during compute.
__global__ __launch_bounds__(256) void attn7(
    const u16* __restrict__ Qh, const u16* __restrict__ Ql,
    const u16* __restrict__ Kh, const u16* __restrict__ Kl,
    const u16* __restrict__ Vph, const u16* __restrict__ Vpl,
    float* __restrict__ H) {
  __shared__ u16 Ksh[2][32 * 256];   // 32 KB (hi, lo)
  __shared__ u16 Vsh[2][256 * 32];   // 32 KB (hi, lo)
  __shared__ u16 P[4][2][16 * 56];   // 14 KB
  const int t = threadIdx.x, l = t & 63, w = t >> 6;
  const int b = blockIdx.x & 7;
  const int pidx = blockIdx.x >> 3;
  int g = 0, acc_ = 0;
  while (acc_ + (8 - (g >> 2)) <= pidx) { acc_ += 8 - (g >> 2); ++g; }
  const int qt = 31 - g;                         // descending q tile
  const int c = pidx - acc_;
  const int kbeg = c * 256;
  const int q0 = qt * 64 + w * 16;
  const int kend_blk = min(kbeg + 256, qt * 64 + 64);
  const int lr = l & 15, lk = l >> 4;

  const u16* Qhp = Qh + (long)(b * Nn + q0 + lr) * Dd;
  const u16* Qlp = Ql + (long)(b * Nn + q0 + lr) * Dd;
  short8 qhf[8], qlf[8];
  #pragma unroll
  for (int cc = 0; cc < 8; ++cc) {
    qhf[cc] = *(const short8*)(Qhp + cc * 32 + lk * 8);
    qlf[cc] = *(const short8*)(Qlp + cc * 32 + lk * 8);
  }

  const f32x4 zv = {0.f, 0.f, 0.f, 0.f};
  f32x4 o[16];
  #pragma unroll
  for (int i = 0; i < 16; ++i) o[i] = zv;

  u16* Ph = &P[w][0][0];
  u16* Pl = &P[w][1][0];
  const u16* Khb = Kh + (long)b * Nn * Dd;
  const u16* Klb = Kl + (long)b * Nn * Dd;
  const u16* Vphb = Vph + (long)b * Dd * Nn;
  const u16* Vplb = Vpl + (long)b * Dd * Nn;
  char* Kc0 = (char*)&Ksh[0][0];
  char* Kc1 = (char*)&Ksh[1][0];
  char* Vc0 = (char*)&Vsh[0][0];
  char* Vc1 = (char*)&Vsh[1][0];
  const int xr = (lr & 7) << 4;              // read-side swizzle
  const int ksr = t & 31, ksc = t >> 5;      // K staging: 16 rows per 16-lane phase

  uint4 ka[4], kb[4], va[4], vb[4];
  {
    const long krow = (long)(kbeg + ksr) * Dd + ksc * 32;
    const u16* vph = Vphb + (long)(kbeg >> 5) * (Dd * 32) + t * 32;
    const u16* vpl = Vplb + (long)(kbeg >> 5) * (Dd * 32) + t * 32;
    #pragma unroll
    for (int i = 0; i < 4; ++i) {
      ka[i] = *(const uint4*)(Khb + krow + i * 8);
      kb[i] = *(const uint4*)(Klb + krow + i * 8);
      va[i] = *(const uint4*)(vph + i * 8);
      vb[i] = *(const uint4*)(vpl + i * 8);
    }
  }

  for (int k0 = kbeg; k0 < kend_blk; k0 += 32) {
    // ---- write staged regs to LDS (LDS free here) ----
    #pragma unroll
    for (int i = 0; i < 4; ++i) {
      const int ko = (ksr * 512 + ksc * 64 + i * 16) ^ ((ksr & 7) << 4);
      const int vo = (t * 64 + i * 16) ^ ((t & 7) << 4);
      *(uint4*)(Kc0 + ko) = ka[i];
      *(uint4*)(Kc1 + ko) = kb[i];
      *(uint4*)(Vc0 + vo) = va[i];
      *(uint4*)(Vc1 + vo) = vb[i];
    }
    __syncthreads();
    // ---- prefetch next tile into regs (hides under compute) ----
    if (k0 + 32 < kend_blk) {
      const long krow = (long)(k0 + 32 + ksr) * Dd + ksc * 32;
      const u16* vph = Vphb + (long)((k0 + 32) >> 5) * (Dd * 32) + t * 32;
      const u16* vpl = Vplb + (long)((k0 + 32) >> 5) * (Dd * 32) + t * 32;
      #pragma unroll
      for (int i = 0; i < 4; ++i) {
        ka[i] = *(const uint4*)(Khb + krow + i * 8);
        kb[i] = *(const uint4*)(Klb + krow + i * 8);
        va[i] = *(const uint4*)(vph + i * 8);
        vb[i] = *(const uint4*)(vpl + i * 8);
      }
    }

    if (k0 <= q0 + 15) {
      f32x4 s0 = zv, s1 = zv;
      __builtin_amdgcn_s_setprio(1);
      #pragma unroll
      for (int cc = 0; cc < 8; ++cc) {
        const int ko = (lr * 512 + cc * 64 + lk * 16) ^ xr;
        short8 kh0 = *(const short8*)(Kc0 + ko);
        short8 kl0 = *(const short8*)(Kc1 + ko);
        short8 kh1 = *(const short8*)(Kc0 + ko + 8192);
        short8 kl1 = *(const short8*)(Kc1 + ko + 8192);
        s0 = __builtin_amdgcn_mfma_f32_16x16x32_bf16(qhf[cc], kh0, s0, 0, 0, 0);
        s0 = __builtin_amdgcn_mfma_f32_16x16x32_bf16(qhf[cc], kl0, s0, 0, 0, 0);
        s0 = __builtin_amdgcn_mfma_f32_16x16x32_bf16(qlf[cc], kh0, s0, 0, 0, 0);
        s1 = __builtin_amdgcn_mfma_f32_16x16x32_bf16(qhf[cc], kh1, s1, 0, 0, 0);
        s1 = __builtin_amdgcn_mfma_f32_16x16x32_bf16(qhf[cc], kl1, s1, 0, 0, 0);
        s1 = __builtin_amdgcn_mfma_f32_16x16x32_bf16(qlf[cc], kh1, s1, 0, 0, 0);
      }
      __builtin_amdgcn_s_setprio(0);
      // relu + causal mask -> split P (per-wave private LDS, wave-synchronous)
      #pragma unroll
      for (int r = 0; r < 4; ++r) {
        const int i = q0 + lk * 4 + r;
        {
          const int j = k0 + lr;
          float v = s0[r];
          v = (j <= i && v > 0.0f) ? v : 0.0f;
          u16 hi, lo; split2(v, hi, lo);
          Ph[(lk * 4 + r) * 56 + lr] = hi;
          Pl[(lk * 4 + r) * 56 + lr] = lo;
        }
        {
          const int j = k0 + 16 + lr;
          float v = s1[r];
          v = (j <= i && v > 0.0f) ? v : 0.0f;
          u16 hi, lo; split2(v, hi, lo);
          Ph[(lk * 4 + r) * 56 + 16 + lr] = hi;
          Pl[(lk * 4 + r) * 56 + 16 + lr] = lo;
        }
      }
      short8 pfh = *(const short8*)(Ph + lr * 56 + lk * 8);
      short8 pfl = *(const short8*)(Pl + lr * 56 + lk * 8);
      __builtin_amdgcn_s_setprio(1);
      #pragma unroll
      for (int dt = 0; dt < 16; ++dt) {
        const int vo = ((dt * 16 + lr) * 64 + lk * 16) ^ xr;
        short8 vh = *(const short8*)(Vc0 + vo);
        short8 vl = *(const short8*)(Vc1 + vo);
        o[dt] = __builtin_amdgcn_mfma_f32_16x16x32_bf16(pfh, vh, o[dt], 0, 0, 0);
        o[dt] = __builtin_amdgcn_mfma_f32_16x16x32_bf16(pfh, vl, o[dt], 0, 0, 0);
        o[dt] = __builtin_amdgcn_mfma_f32_16x16x32_bf16(pfl, vh, o[dt], 0, 0, 0);
      }
      __builtin_amdgcn_s_setprio(0);
    }
    __syncthreads();
  }

  #pragma unroll
  for (int r = 0; r < 4; ++r) {
    const int i = q0 + lk * 4 + r;
    const float sc = 1.0f / (float)(i + 1);
    float* Hp = H + (long)(b * Nn + i) * Dd;
    #pragma unroll
    for (int dt = 0; dt < 16; ++dt)
      atomicAdd(Hp + dt * 16 + lr, o[dt][r] * sc);
  }
}

extern "C" void kernel_launch(void* const* d_in, const int* in_sizes, int n_in,
                              void* d_out, int out_size, void* d_ws, size_t ws_size,
                              hipStream_t stream) {
  const float* x    = (const float*)d_in[0];
  const float* wpe  = (const float*)d_in[1];
  const float* Wq   = (const float*)d_in[2];
  const float* Wk   = (const float*)d_in[3];
  const float* Wv   = (const float*)d_in[4];
  const float* ln1g = (const float*)d_in[5];
  const float* ln1b = (const float*)d_in[6];
  const float* W1   = (const float*)d_in[7];
  const float* b1   = (const float*)d_in[8];
  const float* W2   = (const float*)d_in[9];
  const float* b2   = (const float*)d_in[10];
  const float* ln2g = (const float*)d_in[11];
  const float* ln2b = (const float*)d_in[12];

  char* p = (char*)d_ws;
  auto alloc = [&](size_t bytes) -> void* {
    void* r = (void*)p;
    p += (bytes + 255) & ~(size_t)255;
    return r;
  };
  float* H = (float*)alloc((size_t)Mm * Dd * 4);
  u16* Hh  = (u16*)alloc((size_t)Mm * Dd * 2);
  u16* Hl  = (u16*)alloc((size_t)Mm * Dd * 2);
  u16* Qh_ = (u16*)alloc((size_t)Mm * Dd * 2);
  u16* Ql_ = (u16*)alloc((size_t)Mm * Dd * 2);
  u16* Kh_ = (u16*)alloc((size_t)Mm * Dd * 2);
  u16* Kl_ = (u16*)alloc((size_t)Mm * Dd * 2);
  u16* Vh_ = (u16*)alloc((size_t)Mm * Dd * 2);
  u16* Vl_ = (u16*)alloc((size_t)Mm * Dd * 2);
  const size_t wsz = (size_t)Ll * Dd * Dd * 2;
  u16* Wqh = (u16*)alloc(wsz); u16* Wql = (u16*)alloc(wsz);
  u16* Wkh = (u16*)alloc(wsz); u16* Wkl = (u16*)alloc(wsz);
  u16* Wvh = (u16*)alloc(wsz); u16* Wvl = (u16*)alloc(wsz);
  u16* W1h = (u16*)alloc(wsz); u16* W1l = (u16*)alloc(wsz);
  u16* W2h = (u16*)alloc(wsz); u16* W2l = (u16*)alloc(wsz);

  prep_w3<<<1024, 256, 0, stream>>>(Wq, Wk, Wv, W1, W2,
      Wqh, Wql, Wkh, Wkl, Wvh, Wvl, W1h, W1l, W2h, W2l);
  add_pe3<<<Mm * Dd / 4 / 256, 256, 0, stream>>>(x, wpe, H, Hh, Hl);

  const dim3 g1(Mm / 64, Dd / 64, 1);       // (256, 4, 1)
  const dim3 gv(Dd / 64, Nn / 64, Bb);      // (4, 32, 8)
  const long NDl = (long)Nn * Dd;

  for (int l = 0; l < Ll; ++l) {
    const int wo = l * Dd * Dd;
    gemm3<0><<<g1, 256, 0, stream>>>(Hh, Hl, Wqh + wo, Wql + wo, Qh_, Ql_, nullptr, Dd, 0, 0);
    gemm3<0><<<g1, 256, 0, stream>>>(Hh, Hl, Wkh + wo, Wkl + wo, Kh_, Kl_, nullptr, Dd, 0, 0);
    gemm3<3><<<gv, 256, 0, stream>>>(Wvh + wo, Wvl + wo, Hh, Hl, Vh_, Vl_, nullptr, Nn, NDl, NDl);
    attn7<<<1152, 256, 0, stream>>>(Qh_, Ql_, Kh_, Kl_, Vh_, Vl_, H);
    ln3<<<Mm / 4, 256, 0, stream>>>(H, H, Hh, Hl, ln1g + l * Dd, ln1b + l * Dd);
    // h1 reuses Q buffers (Q dead after attn)
    gemm3<1><<<g1, 256, 0, stream>>>(Hh, Hl, W1h + wo, W1l + wo, Qh_, Ql_, b1 + l * Dd, Dd, 0, 0);
    gemm3<2><<<g1, 256, 0, stream>>>(Qh_, Ql_, W2h + wo, W2l + wo, (void*)H, nullptr, b2 + l * Dd, Dd, 0, 0);
    float* lnout = (l == Ll - 1) ? (float*)d_out : H;
    ln3<<<Mm / 4, 256, 0, stream>>>(H, lnout, Hh, Hl, ln2g + l * Dd, ln2b + l * Dd);
  }
}

// Round 8
// 979.093 us; speedup vs baseline: 1.7890x; 1.7890x over previous
//
#include <hip/hip_runtime.h>

#define Dd 256
#define Nn 2048
#define Bb 8
#define Ll 4
#define Mm (Bb*Nn)   // 16384

typedef __attribute__((ext_vector_type(8))) short short8;
typedef __attribute__((ext_vector_type(4))) float f32x4;
typedef unsigned short u16;

__device__ __forceinline__ u16 f2bf(float f) {
  unsigned int u = __float_as_uint(f);
  u = (u + 0x7FFFu + ((u >> 16) & 1u)) >> 16;
  return (u16)u;
}
__device__ __forceinline__ float bf2f(u16 h) {
  return __uint_as_float(((unsigned int)h) << 16);
}
__device__ __forceinline__ void split2(float v, u16& hi, u16& lo) {
  hi = f2bf(v);
  lo = f2bf(v - bf2f(hi));
}

// ---- weight prep: split-transpose Wt[l][e][d] = W[l][d][e] into bf16 hi/lo ----
__global__ void prep_w3(const float* __restrict__ Wq, const float* __restrict__ Wk,
                        const float* __restrict__ Wv, const float* __restrict__ W1,
                        const float* __restrict__ W2,
                        u16* __restrict__ qh, u16* __restrict__ ql,
                        u16* __restrict__ kh, u16* __restrict__ kl,
                        u16* __restrict__ vh, u16* __restrict__ vl,
                        u16* __restrict__ w1h, u16* __restrict__ w1l,
                        u16* __restrict__ w2h, u16* __restrict__ w2l) {
  int idx = blockIdx.x * 256 + threadIdx.x;    // < L*D*D
  int l = idx >> 16, rem = idx & 65535;
  int e = rem >> 8, d = rem & 255;
  int src = (l << 16) | (d << 8) | e;
  u16 h, lo;
  split2(Wq[src], h, lo); qh[idx] = h;  ql[idx] = lo;
  split2(Wk[src], h, lo); kh[idx] = h;  kl[idx] = lo;
  split2(Wv[src], h, lo); vh[idx] = h;  vl[idx] = lo;
  split2(W1[src], h, lo); w1h[idx] = h; w1l[idx] = lo;
  split2(W2[src], h, lo); w2h[idx] = h; w2l[idx] = lo;
}

// ---- H = x + wpe ; split stores ----
__global__ void add_pe3(const float* __restrict__ x, const float* __restrict__ wpe,
                        float* __restrict__ H, u16* __restrict__ Hh, u16* __restrict__ Hl) {
  int idx = blockIdx.x * 256 + threadIdx.x;    // float4 index
  int nd = (idx << 2) & (Nn * Dd - 1);
  float4 xv = ((const float4*)x)[idx];
  float4 pv = *(const float4*)(wpe + nd);
  float4 h;
  h.x = xv.x + pv.x; h.y = xv.y + pv.y; h.z = xv.z + pv.z; h.w = xv.w + pv.w;
  ((float4*)H)[idx] = h;
  ushort4 hv, lv;
  split2(h.x, hv.x, lv.x); split2(h.y, hv.y, lv.y);
  split2(h.z, hv.z, lv.z); split2(h.w, hv.w, lv.w);
  ((ushort4*)Hh)[idx] = hv;
  ((ushort4*)Hl)[idx] = lv;
}

// ---- layernorm: 1 wave per row; fp32 out + split bf16 out ----
__global__ __launch_bounds__(256) void ln3(const float* __restrict__ Hin,
      float* __restrict__ Hout, u16* __restrict__ Hh, u16* __restrict__ Hl,
      const float* __restrict__ g, const float* __restrict__ b) {
  int w = threadIdx.x >> 6, l = threadIdx.x & 63;
  int row = blockIdx.x * 4 + w;
  const float4 h = *(const float4*)(Hin + row * Dd + l * 4);
  float s = h.x + h.y + h.z + h.w;
  #pragma unroll
  for (int m = 1; m < 64; m <<= 1) s += __shfl_xor(s, m, 64);
  float mu = s * (1.0f / Dd);
  float4 c; c.x = h.x - mu; c.y = h.y - mu; c.z = h.z - mu; c.w = h.w - mu;
  float sq = c.x*c.x + c.y*c.y + c.z*c.z + c.w*c.w;
  #pragma unroll
  for (int m = 1; m < 64; m <<= 1) sq += __shfl_xor(sq, m, 64);
  float rs = rsqrtf(sq * (1.0f / Dd) + 1e-5f);
  float4 gv = *(const float4*)(g + l * 4);
  float4 bv = *(const float4*)(b + l * 4);
  float4 y;
  y.x = c.x * rs * gv.x + bv.x;
  y.y = c.y * rs * gv.y + bv.y;
  y.z = c.z * rs * gv.z + bv.z;
  y.w = c.w * rs * gv.w + bv.w;
  *(float4*)(Hout + row * Dd + l * 4) = y;
  ushort4 hv, lv;
  split2(y.x, hv.x, lv.x); split2(y.y, hv.y, lv.y);
  split2(y.z, hv.z, lv.z); split2(y.w, hv.w, lv.w);
  *(ushort4*)(Hh + row * Dd + l * 4) = hv;
  *(ushort4*)(Hl + row * Dd + l * 4) = lv;
}

// ---- NT GEMM, bf16x3 (split hi/lo), fp32 acc, 128x64 tile ----
// EPI 0: split store; EPI 1: +bias, relu, split store; EPI 2: +bias, fp32 C +=
// EPI 3: split store in 32-col panel layout [col/32][row(256)][col&31] (for V)
template<int EPI>
__global__ __launch_bounds__(256) void gemm4(
    const u16* __restrict__ Ah, const u16* __restrict__ Al,
    const u16* __restrict__ Bh, const u16* __restrict__ Bl,
    void* __restrict__ Ch, void* __restrict__ Cl, const float* __restrict__ bias,
    int ldc, long sBz, long sCz) {
  __shared__ u16 Sa[2][128 * 40];
  __shared__ u16 Sb[2][64 * 40];
  const int t = threadIdx.x;
  const int l = t & 63, w = t >> 6;
  const int m0 = blockIdx.x * 128, n0 = blockIdx.y * 64;
  Bh += (long)blockIdx.z * sBz;
  Bl += (long)blockIdx.z * sBz;
  const int lr = l & 15, lk = l >> 4;
  const int ar = t >> 1, ac = (t & 1) << 1;  // A staging: row, chunk-pair
  const int br = t >> 2, bc = t & 3;         // B staging: row, chunk

  const f32x4 zv = {0.f, 0.f, 0.f, 0.f};
  f32x4 acc[2][4];
  #pragma unroll
  for (int i = 0; i < 2; ++i)
    #pragma unroll
    for (int j = 0; j < 4; ++j) acc[i][j] = zv;

  for (int kt = 0; kt < 8; ++kt) {
    const int k0 = kt * 32;
    *(uint4*)(&Sa[0][ar * 40 + ac * 8])     = *(const uint4*)(Ah + (long)(m0 + ar) * 256 + k0 + ac * 8);
    *(uint4*)(&Sa[0][ar * 40 + ac * 8 + 8]) = *(const uint4*)(Ah + (long)(m0 + ar) * 256 + k0 + ac * 8 + 8);
    *(uint4*)(&Sa[1][ar * 40 + ac * 8])     = *(const uint4*)(Al + (long)(m0 + ar) * 256 + k0 + ac * 8);
    *(uint4*)(&Sa[1][ar * 40 + ac * 8 + 8]) = *(const uint4*)(Al + (long)(m0 + ar) * 256 + k0 + ac * 8 + 8);
    *(uint4*)(&Sb[0][br * 40 + bc * 8])     = *(const uint4*)(Bh + (long)(n0 + br) * 256 + k0 + bc * 8);
    *(uint4*)(&Sb[1][br * 40 + bc * 8])     = *(const uint4*)(Bl + (long)(n0 + br) * 256 + k0 + bc * 8);
    __syncthreads();
    short8 ah[2], al[2], bh[4], bl[4];
    #pragma unroll
    for (int mi = 0; mi < 2; ++mi) {
      ah[mi] = *(const short8*)(&Sa[0][(w * 32 + mi * 16 + lr) * 40 + lk * 8]);
      al[mi] = *(const short8*)(&Sa[1][(w * 32 + mi * 16 + lr) * 40 + lk * 8]);
    }
    #pragma unroll
    for (int ni = 0; ni < 4; ++ni) {
      bh[ni] = *(const short8*)(&Sb[0][(ni * 16 + lr) * 40 + lk * 8]);
      bl[ni] = *(const short8*)(&Sb[1][(ni * 16 + lr) * 40 + lk * 8]);
    }
    #pragma unroll
    for (int mi = 0; mi < 2; ++mi)
      #pragma unroll
      for (int ni = 0; ni < 4; ++ni) {
        acc[mi][ni] = __builtin_amdgcn_mfma_f32_16x16x32_bf16(ah[mi], bh[ni], acc[mi][ni], 0, 0, 0);
        acc[mi][ni] = __builtin_amdgcn_mfma_f32_16x16x32_bf16(ah[mi], bl[ni], acc[mi][ni], 0, 0, 0);
        acc[mi][ni] = __builtin_amdgcn_mfma_f32_16x16x32_bf16(al[mi], bh[ni], acc[mi][ni], 0, 0, 0);
      }
    __syncthreads();
  }

  #pragma unroll
  for (int mi = 0; mi < 2; ++mi) {
    #pragma unroll
    for (int ni = 0; ni < 4; ++ni) {
      const int row = m0 + w * 32 + mi * 16 + lk * 4;
      const int col = n0 + ni * 16 + lr;
      if constexpr (EPI == 0) {
        u16* Chb = (u16*)Ch + (long)blockIdx.z * sCz;
        u16* Clb = (u16*)Cl + (long)blockIdx.z * sCz;
        #pragma unroll
        for (int r = 0; r < 4; ++r) {
          u16 hi, lo; split2(acc[mi][ni][r], hi, lo);
          Chb[(long)(row + r) * ldc + col] = hi;
          Clb[(long)(row + r) * ldc + col] = lo;
        }
      } else if constexpr (EPI == 1) {
        u16* Chb = (u16*)Ch;
        u16* Clb = (u16*)Cl;
        const float bi = bias[col];
        #pragma unroll
        for (int r = 0; r < 4; ++r) {
          float v = fmaxf(acc[mi][ni][r] + bi, 0.0f);
          u16 hi, lo; split2(v, hi, lo);
          Chb[(long)(row + r) * ldc + col] = hi;
          Clb[(long)(row + r) * ldc + col] = lo;
        }
      } else if constexpr (EPI == 2) {
        float* Cf = (float*)Ch;
        const float bi = bias[col];
        #pragma unroll
        for (int r = 0; r < 4; ++r)
          Cf[(long)(row + r) * ldc + col] += acc[mi][ni][r] + bi;
      } else {
        // V panel layout: [col/32][row(0..255)][col&31]
        u16* Chb = (u16*)Ch + (long)blockIdx.z * sCz;
        u16* Clb = (u16*)Cl + (long)blockIdx.z * sCz;
        const long pbase = (long)(col >> 5) * (Dd * 32) + (col & 31);
        #pragma unroll
        for (int r = 0; r < 4; ++r) {
          u16 hi, lo; split2(acc[mi][ni][r], hi, lo);
          Chb[pbase + (long)(row + r) * 32] = hi;
          Clb[pbase + (long)(row + r) * 32] = lo;
        }
      }
    }
  }
}

// ---- causal relu attention, bf16x3, key-split, LDS-staged K/V ----
// R4 structure (2048-block ascending grid), conflict-free swizzle maps:
//   K chunk swizzle: chunk ^ ((row&7)<<2)   (reads & writes 2-way = free)
//   V chunk swizzle: chunk ^ (row&3)        (reads & writes 2-way = free)
__global__ __launch_bounds__(256) void attn8(
    const u16* __restrict__ Qh, const u16* __restrict__ Ql,
    const u16* __restrict__ Kh, const u16* __restrict__ Kl,
    const u16* __restrict__ Vph, const u16* __restrict__ Vpl,
    float* __restrict__ H) {
  __shared__ u16 Ksh[2][32 * 256];   // 32 KB (hi, lo)
  __shared__ u16 Vsh[2][256 * 32];   // 32 KB (hi, lo)
  __shared__ u16 P[4][2][16 * 56];   // 14 KB
  const int t = threadIdx.x, l = t & 63, w = t >> 6;
  const int bx = blockIdx.x;
  const int b = bx & 7;
  const int c = (bx >> 3) & 7;
  const int qt = bx >> 6;
  const int kbeg = c * 256;
  if (kbeg > qt * 64 + 63) return;           // fully above diagonal
  const int q0 = qt * 64 + w * 16;
  const int kend_blk = min(kbeg + 256, qt * 64 + 64);
  const int lr = l & 15, lk = l >> 4;

  const u16* Qhp = Qh + (long)(b * Nn + q0 + lr) * Dd;
  const u16* Qlp = Ql + (long)(b * Nn + q0 + lr) * Dd;
  short8 qhf[8], qlf[8];
  #pragma unroll
  for (int cc = 0; cc < 8; ++cc) {
    qhf[cc] = *(const short8*)(Qhp + cc * 32 + lk * 8);
    qlf[cc] = *(const short8*)(Qlp + cc * 32 + lk * 8);
  }

  const f32x4 zv = {0.f, 0.f, 0.f, 0.f};
  f32x4 o[16];
  #pragma unroll
  for (int i = 0; i < 16; ++i) o[i] = zv;

  u16* Ph = &P[w][0][0];
  u16* Pl = &P[w][1][0];
  const u16* Khb = Kh + (long)b * Nn * Dd;
  const u16* Klb = Kl + (long)b * Nn * Dd;
  const u16* Vphb = Vph + (long)b * Dd * Nn;
  const u16* Vplb = Vpl + (long)b * Dd * Nn;
  char* Kc0 = (char*)&Ksh[0][0];
  char* Kc1 = (char*)&Ksh[1][0];
  char* Vc0 = (char*)&Vsh[0][0];
  char* Vc1 = (char*)&Vsh[1][0];
  const int kr = (w << 3) + (l >> 3);        // K stage: row 0..31 (wave slab)
  const int kc = l & 7;                      // chunk group within row
  const int krx = (l >> 3) << 2;             // (row&7)<<2 chunk swizzle

  for (int k0 = kbeg; k0 < kend_blk; k0 += 32) {
    // ---- cooperative stage: K rows k0..k0+31 (hi/lo), V panel k0>>5 (hi/lo) ----
    {
      const u16* krp0 = Khb + (long)(k0 + kr) * Dd;
      const u16* krp1 = Klb + (long)(k0 + kr) * Dd;
      const u16* vpp0 = Vphb + (long)(k0 >> 5) * (Dd * 32);
      const u16* vpp1 = Vplb + (long)(k0 >> 5) * (Dd * 32);
      #pragma unroll
      for (int i = 0; i < 4; ++i) {
        const int kchunk = i * 8 + kc;
        const int ko = kr * 512 + ((kchunk ^ krx) << 4);
        uint4 ka = *(const uint4*)(krp0 + kchunk * 8);
        uint4 kb = *(const uint4*)(krp1 + kchunk * 8);
        *(uint4*)(Kc0 + ko) = ka;
        *(uint4*)(Kc1 + ko) = kb;
        const int vd = i * 64 + (t >> 2);
        const int vo = vd * 64 + (((t & 3) ^ (vd & 3)) << 4);
        uint4 va = *(const uint4*)(vpp0 + (long)vd * 32 + (t & 3) * 8);
        uint4 vb = *(const uint4*)(vpp1 + (long)vd * 32 + (t & 3) * 8);
        *(uint4*)(Vc0 + vo) = va;
        *(uint4*)(Vc1 + vo) = vb;
      }
    }
    __syncthreads();

    if (k0 <= q0 + 15) {
      f32x4 s0 = zv, s1 = zv;
      #pragma unroll
      for (int cc = 0; cc < 8; ++cc) {
        const int ko = lr * 512 + ((((cc << 2) + lk) ^ ((lr & 7) << 2)) << 4);
        short8 kh0 = *(const short8*)(Kc0 + ko);
        short8 kl0 = *(const short8*)(Kc1 + ko);
        short8 kh1 = *(const short8*)(Kc0 + ko + 8192);
        short8 kl1 = *(const short8*)(Kc1 + ko + 8192);
        s0 = __builtin_amdgcn_mfma_f32_16x16x32_bf16(qhf[cc], kh0, s0, 0, 0, 0);
        s0 = __builtin_amdgcn_mfma_f32_16x16x32_bf16(qhf[cc], kl0, s0, 0, 0, 0);
        s0 = __builtin_amdgcn_mfma_f32_16x16x32_bf16(qlf[cc], kh0, s0, 0, 0, 0);
        s1 = __builtin_amdgcn_mfma_f32_16x16x32_bf16(qhf[cc], kh1, s1, 0, 0, 0);
        s1 = __builtin_amdgcn_mfma_f32_16x16x32_bf16(qhf[cc], kl1, s1, 0, 0, 0);
        s1 = __builtin_amdgcn_mfma_f32_16x16x32_bf16(qlf[cc], kh1, s1, 0, 0, 0);
      }
      // relu + causal mask -> split P (per-wave private LDS, wave-synchronous)
      #pragma unroll
      for (int r = 0; r < 4; ++r) {
        const int i = q0 + lk * 4 + r;
        {
          const int j = k0 + lr;
          float v = s0[r];
          v = (j <= i && v > 0.0f) ? v : 0.0f;
          u16 hi, lo; split2(v, hi, lo);
          Ph[(lk * 4 + r) * 56 + lr] = hi;
          Pl[(lk * 4 + r) * 56 + lr] = lo;
        }
        {
          const int j = k0 + 16 + lr;
          float v = s1[r];
          v = (j <= i && v > 0.0f) ? v : 0.0f;
          u16 hi, lo; split2(v, hi, lo);
          Ph[(lk * 4 + r) * 56 + 16 + lr] = hi;
          Pl[(lk * 4 + r) * 56 + 16 + lr] = lo;
        }
      }
      short8 pfh = *(const short8*)(Ph + lr * 56 + lk * 8);
      short8 pfl = *(const short8*)(Pl + lr * 56 + lk * 8);
      #pragma unroll
      for (int dt = 0; dt < 16; ++dt) {
        const int vo = (dt * 16 + lr) * 64 + ((lk ^ (lr & 3)) << 4);
        short8 vh = *(const short8*)(Vc0 + vo);
        short8 vl = *(const short8*)(Vc1 + vo);
        o[dt] = __builtin_amdgcn_mfma_f32_16x16x32_bf16(pfh, vh, o[dt], 0, 0, 0);
        o[dt] = __builtin_amdgcn_mfma_f32_16x16x32_bf16(pfh, vl, o[dt], 0, 0, 0);
        o[dt] = __builtin_amdgcn_mfma_f32_16x16x32_bf16(pfl, vh, o[dt], 0, 0, 0);
      }
    }
    __syncthreads();
  }

  if (kbeg <= q0 + 15) {
    #pragma unroll
    for (int r = 0; r < 4; ++r) {
      const int i = q0 + lk * 4 + r;
      const float sc = 1.0f / (float)(i + 1);
      float* Hp = H + (long)(b * Nn + i) * Dd;
      #pragma unroll
      for (int dt = 0; dt < 16; ++dt)
        atomicAdd(Hp + dt * 16 + lr, o[dt][r] * sc);
    }
  }
}

extern "C" void kernel_launch(void* const* d_in, const int* in_sizes, int n_in,
                              void* d_out, int out_size, void* d_ws, size_t ws_size,
                              hipStream_t stream) {
  const float* x    = (const float*)d_in[0];
  const float* wpe  = (const float*)d_in[1];
  const float* Wq   = (const float*)d_in[2];
  const float* Wk   = (const float*)d_in[3];
  const float* Wv   = (const float*)d_in[4];
  const float* ln1g = (const float*)d_in[5];
  const float* ln1b = (const float*)d_in[6];
  const float* W1   = (const float*)d_in[7];
  const float* b1   = (const float*)d_in[8];
  const float* W2   = (const float*)d_in[9];
  const float* b2   = (const float*)d_in[10];
  const float* ln2g = (const float*)d_in[11];
  const float* ln2b = (const float*)d_in[12];

  char* p = (char*)d_ws;
  auto alloc = [&](size_t bytes) -> void* {
    void* r = (void*)p;
    p += (bytes + 255) & ~(size_t)255;
    return r;
  };
  float* H = (float*)alloc((size_t)Mm * Dd * 4);
  u16* Hh  = (u16*)alloc((size_t)Mm * Dd * 2);
  u16* Hl  = (u16*)alloc((size_t)Mm * Dd * 2);
  u16* Qh_ = (u16*)alloc((size_t)Mm * Dd * 2);
  u16* Ql_ = (u16*)alloc((size_t)Mm * Dd * 2);
  u16* Kh_ = (u16*)alloc((size_t)Mm * Dd * 2);
  u16* Kl_ = (u16*)alloc((size_t)Mm * Dd * 2);
  u16* Vh_ = (u16*)alloc((size_t)Mm * Dd * 2);
  u16* Vl_ = (u16*)alloc((size_t)Mm * Dd * 2);
  const size_t wsz = (size_t)Ll * Dd * Dd * 2;
  u16* Wqh = (u16*)alloc(wsz); u16* Wql = (u16*)alloc(wsz);
  u16* Wkh = (u16*)alloc(wsz); u16* Wkl = (u16*)alloc(wsz);
  u16* Wvh = (u16*)alloc(wsz); u16* Wvl = (u16*)alloc(wsz);
  u16* W1h = (u16*)alloc(wsz); u16* W1l = (u16*)alloc(wsz);
  u16* W2h = (u16*)alloc(wsz); u16* W2l = (u16*)alloc(wsz);

  prep_w3<<<1024, 256, 0, stream>>>(Wq, Wk, Wv, W1, W2,
      Wqh, Wql, Wkh, Wkl, Wvh, Wvl, W1h, W1l, W2h, W2l);
  add_pe3<<<Mm * Dd / 4 / 256, 256, 0, stream>>>(x, wpe, H, Hh, Hl);

  const dim3 g1(Mm / 128, Dd / 64, 1);      // (128, 4, 1)
  const dim3 gv(Dd / 128, Nn / 64, Bb);     // (2, 32, 8)
  const long NDl = (long)Nn * Dd;

  for (int l = 0; l < Ll; ++l) {
    const int wo = l * Dd * Dd;
    gemm4<0><<<g1, 256, 0, stream>>>(Hh, Hl, Wqh + wo, Wql + wo, Qh_, Ql_, nullptr, Dd, 0, 0);
    gemm4<0><<<g1, 256, 0, stream>>>(Hh, Hl, Wkh + wo, Wkl + wo, Kh_, Kl_, nullptr, Dd, 0, 0);
    gemm4<3><<<gv, 256, 0, stream>>>(Wvh + wo, Wvl + wo, Hh, Hl, Vh_, Vl_, nullptr, Nn, NDl, NDl);
    attn8<<<2048, 256, 0, stream>>>(Qh_, Ql_, Kh_, Kl_, Vh_, Vl_, H);
    ln3<<<Mm / 4, 256, 0, stream>>>(H, H, Hh, Hl, ln1g + l * Dd, ln1b + l * Dd);
    // h1 reuses Q buffers (Q dead after attn)
    gemm4<1><<<g1, 256, 0, stream>>>(Hh, Hl, W1h + wo, W1l + wo, Qh_, Ql_, b1 + l * Dd, Dd, 0, 0);
    gemm4<2><<<g1, 256, 0, stream>>>(Qh_, Ql_, W2h + wo, W2l + wo, (void*)H, nullptr, b2 + l * Dd, Dd, 0, 0);
    float* lnout = (l == Ll - 1) ? (float*)d_out : H;
    ln3<<<Mm / 4, 256, 0, stream>>>(H, lnout, Hh, Hl, ln2g + l * Dd, ln2b + l * Dd);
  }
}